// Round 8
// baseline (163.834 us; speedup 1.0000x reference)
//
#include <hip/hip_runtime.h>
#include <hip/hip_bf16.h>

typedef __attribute__((ext_vector_type(8))) short bf16x8;   // 8 bf16 = 4 VGPR (MFMA A/B frag)
typedef __attribute__((ext_vector_type(4))) float f32x4;    // MFMA C/D frag

#define DEVI __device__ __forceinline__

constexpr int SEQ_   = 2048;
constexpr int HEADS  = 16;
constexpr int DHEAD  = 64;
constexpr int DMODEL = 1024;

DEVI unsigned short f2bf(float x) {
  __hip_bfloat16 h = __float2bfloat16(x);   // RNE
  return __builtin_bit_cast(unsigned short, h);
}

DEVI f32x4 MFMA(bf16x8 a, bf16x8 b, f32x4 c) {
  return __builtin_amdgcn_mfma_f32_16x16x32_bf16(a, b, c, 0, 0, 0);
}

// ---------------------------------------------------------------- convert ---
__global__ void conv3_kernel(const float* s0, const float* s1, const float* s2,
                             unsigned short* d0, unsigned short* d1, unsigned short* d2,
                             int n) {
  const float* s = (blockIdx.y == 0) ? s0 : (blockIdx.y == 1) ? s1 : s2;
  unsigned short* d = (blockIdx.y == 0) ? d0 : (blockIdx.y == 1) ? d1 : d2;
  int i = (blockIdx.x * 256 + threadIdx.x) * 8;
  if (i >= n) return;
  const float4* p = (const float4*)(s + i);
  float4 v0 = p[0], v1 = p[1];
  union { unsigned short u[8]; bf16x8 v; } t;
  t.u[0] = f2bf(v0.x); t.u[1] = f2bf(v0.y); t.u[2] = f2bf(v0.z); t.u[3] = f2bf(v0.w);
  t.u[4] = f2bf(v1.x); t.u[5] = f2bf(v1.y); t.u[6] = f2bf(v1.z); t.u[7] = f2bf(v1.w);
  *(bf16x8*)(d + i) = t.v;
}

// weights (y=0..2, n_w elems) + Er (y=3, n_e elems) in one launch
__global__ void conv4_kernel(const float* s0, const float* s1, const float* s2,
                             const float* s3,
                             unsigned short* d0, unsigned short* d1,
                             unsigned short* d2, unsigned short* d3,
                             int n_w, int n_e) {
  const int y = blockIdx.y;
  const float* s = (y == 0) ? s0 : (y == 1) ? s1 : (y == 2) ? s2 : s3;
  unsigned short* d = (y == 0) ? d0 : (y == 1) ? d1 : (y == 2) ? d2 : d3;
  const int n = (y == 3) ? n_e : n_w;
  int i = (blockIdx.x * 256 + threadIdx.x) * 8;
  if (i >= n) return;
  const float4* p = (const float4*)(s + i);
  float4 v0 = p[0], v1 = p[1];
  union { unsigned short u[8]; bf16x8 v; } t;
  t.u[0] = f2bf(v0.x); t.u[1] = f2bf(v0.y); t.u[2] = f2bf(v0.z); t.u[3] = f2bf(v0.w);
  t.u[4] = f2bf(v1.x); t.u[5] = f2bf(v1.y); t.u[6] = f2bf(v1.z); t.u[7] = f2bf(v1.w);
  *(bf16x8*)(d + i) = t.v;
}

// ------------------------------------------------------------- projection ---
// z==0 (Q): out (b,h,s,d), PRE-SCALED by 0.125 (folds the 1/sqrt(dh)).
// z==1 (K): 4KB tiles in MFMA fragment order.
// z==2 (V): 4KB tiles in MFMA fragment order.
__global__ __launch_bounds__(256) void proj3_kernel(
    const unsigned short* __restrict__ X0, const unsigned short* __restrict__ X1,
    const unsigned short* __restrict__ X2,
    const unsigned short* __restrict__ W0, const unsigned short* __restrict__ W1,
    const unsigned short* __restrict__ W2,
    const float* __restrict__ bi0, const float* __restrict__ bi1,
    const float* __restrict__ bi2,
    unsigned short* __restrict__ o0, unsigned short* __restrict__ o1,
    unsigned short* __restrict__ o2) {
  const int z = blockIdx.z;
  const unsigned short* X = (z == 0) ? X0 : (z == 1) ? X1 : X2;
  const unsigned short* W = (z == 0) ? W0 : (z == 1) ? W1 : W2;
  const float* bias        = (z == 0) ? bi0 : (z == 1) ? bi1 : bi2;
  unsigned short* out      = (z == 0) ? o0 : (z == 1) ? o1 : o2;

  __shared__ unsigned short Abuf[2][128 * 32];
  __shared__ unsigned short Bbuf[2][128 * 32];
  const int tid  = threadIdx.x;
  const int lane = tid & 63, wv = tid >> 6;
  const int q = lane >> 4, r = lane & 15;
  const int wrow = wv >> 1, wcol = wv & 1;
  const int rowA0 = blockIdx.x * 128, colB0 = blockIdx.y * 128;

  const char* Ag = (const char*)(X + (size_t)rowA0 * DMODEL);
  const char* Bg = (const char*)(W + (size_t)colB0 * DMODEL);

  f32x4 acc[4][4] = {};

  auto stage = [&](int ks, int buf) {
    const int koff = ks * 64;
#pragma unroll
    for (int i = 0; i < 2; ++i) {
      const int b   = (i * 256 + tid) * 16;
      const int row = b >> 6, col = b & 63;
      __builtin_amdgcn_global_load_lds(
          (const __attribute__((address_space(1))) void*)(Ag + (size_t)row * (DMODEL * 2) + koff + col),
          (__attribute__((address_space(3))) void*)((char*)&Abuf[buf][0] + i * 4096 + wv * 1024),
          16, 0, 0);
      __builtin_amdgcn_global_load_lds(
          (const __attribute__((address_space(1))) void*)(Bg + (size_t)row * (DMODEL * 2) + koff + col),
          (__attribute__((address_space(3))) void*)((char*)&Bbuf[buf][0] + i * 4096 + wv * 1024),
          16, 0, 0);
    }
  };

  stage(0, 0);
  for (int ks = 0; ks < 32; ++ks) {
    __syncthreads();
    if (ks + 1 < 32) stage(ks + 1, (ks + 1) & 1);
    const unsigned short* A  = &Abuf[ks & 1][0];
    const unsigned short* Bt = &Bbuf[ks & 1][0];
    bf16x8 af[4], bfr[4];
#pragma unroll
    for (int t = 0; t < 4; ++t) {
      af[t]  = *(const bf16x8*)(A  + (wrow * 64 + t * 16 + r) * 32 + q * 8);
      bfr[t] = *(const bf16x8*)(Bt + (wcol * 64 + t * 16 + r) * 32 + q * 8);
    }
#pragma unroll
    for (int m = 0; m < 4; ++m)
#pragma unroll
      for (int n = 0; n < 4; ++n)
        acc[m][n] = MFMA(af[m], bfr[n], acc[m][n]);
  }

#pragma unroll
  for (int m = 0; m < 4; ++m) {
#pragma unroll
    for (int n = 0; n < 4; ++n) {
      const int e  = colB0 + wcol * 64 + n * 16 + r;
      const float bv = bias[e];
      const int h = e >> 6, dd = e & 63;
      const int nrow0 = rowA0 + wrow * 64 + m * 16 + q * 4;
      const int bb = nrow0 >> 11, ss0 = nrow0 & 2047;
      const size_t bh = (size_t)(bb * HEADS + h);
      if (z == 0) {
#pragma unroll
        for (int j = 0; j < 4; ++j)
          out[(bh * SEQ_ + (ss0 + j)) * DHEAD + dd] = f2bf((acc[m][n][j] + bv) * 0.125f);
      } else if (z == 1) {
#pragma unroll
        for (int j = 0; j < 4; ++j) {
          const int s = ss0 + j;
          const size_t off = (bh * 64 + (size_t)(s >> 5)) * 2048
                           + (size_t)(((dd >> 5) * 2 + ((s >> 4) & 1)) * 512)
                           + (size_t)(((((dd & 31) >> 3) << 4) + (s & 15)) * 8)
                           + (dd & 7);
          out[off] = f2bf(acc[m][n][j] + bv);
        }
      } else {
        union { unsigned short u[4]; uint2 v; } pk;
#pragma unroll
        for (int j = 0; j < 4; ++j) pk.u[j] = f2bf(acc[m][n][j] + bv);
        const size_t off = (bh * 64 + (size_t)(ss0 >> 5)) * 2048
                         + (size_t)((dd >> 4) * 512)
                         + (size_t)(((((ss0 & 31) >> 3) << 4) + (dd & 15)) * 8)
                         + (ss0 & 7);
        *(uint2*)&out[off] = pk.v;
      }
    }
  }
}

// -------------------------------------------------------------- attention ---
// 512 blocks x 512 thr (8 waves x 16 rows = 128-row tile/block, tile-per-block,
// no split-K, no reduce). 2 blocks/CU x 8 waves = 16 waves/CU (2x R7's waves).
// Big-first: per-CU total 68 iters == largest block's 68 -> balanced makespan.
// K/V staged via global_load_lds (frag-order tiles, linear, conflict-free);
// Er fresh tiles (2/iter) prefetched 1 iter ahead into ping-ponged regs;
// QEr sliding 3-tile lattice with carry. Fixed-max softmax, direct store.
struct ErF { bf16x8 e10, e11, e20, e21; };

__global__ __launch_bounds__(512, 4) void attn_kernel(
    const unsigned short* __restrict__ qb, const unsigned short* __restrict__ kt,
    const unsigned short* __restrict__ vt, const unsigned short* __restrict__ Er,
    float* __restrict__ out) {
  __shared__ unsigned short k_lds[2][2048];     // frag-order 4KB tile per buf
  __shared__ unsigned short v_lds[2][2048];
  __shared__ unsigned short p_lds[8][16][40];   // per-wave P bounce

  const int tid  = threadIdx.x;
  const int lane = tid & 63, wv = tid >> 6;     // 8 waves
  const int q = lane >> 4, r = lane & 15;

  const int lid = blockIdx.x;
  const int xcd = lid & 7, idx = lid >> 3;      // 64 per XCD
  const int bh  = (xcd << 2) | (idx & 3);       // 4 bh pinned per XCD L2
  const int T   = 15 - (idx >> 2);              // big tiles dispatched first
  const int s0  = T * 128 + wv * 16;            // this wave's 16 rows
  const int nIter = 4 * T + 4;
  const int bb = bh >> 4, hh = bh & 15;

  const unsigned short* qbh = qb + (size_t)bh * SEQ_ * DHEAD;
  const char* ktb = (const char*)(kt + (size_t)bh * 64 * 2048);
  const char* vtb = (const char*)(vt + (size_t)bh * 64 * 2048);
  const f32x4 zero4 = {0.f, 0.f, 0.f, 0.f};

  // waves 0-3 stage K, waves 4-7 stage V (wave-uniform branch)
  const bool isK = (tid < 256);
  const char* sbase = isK ? ktb : vtb;
  const int subt = tid & 255;

  auto stage = [&](int tile, int buf) {
    char* dst = (char*)(isK ? &k_lds[buf][0] : &v_lds[buf][0]) + (wv & 3) * 1024;
    __builtin_amdgcn_global_load_lds(
        (const __attribute__((address_space(1))) void*)(sbase + (size_t)tile * 4096 + subt * 16),
        (__attribute__((address_space(3))) void*)dst, 16, 0, 0);
  };

  auto loadE = [&](ErF& e, int it2) {           // fresh lattice tiles for iter it2
    const int lb = 2032 + it2 * 32 - s0;
    int l1 = lb + 16 + r; l1 = l1 < 2047 ? l1 : 2047;
    int l2 = lb + 32 + r; l2 = l2 < 2047 ? l2 : 2047;
    e.e10 = *(const bf16x8*)(Er + (size_t)l1 * DHEAD + q * 8);
    e.e11 = *(const bf16x8*)(Er + (size_t)l1 * DHEAD + 32 + q * 8);
    e.e20 = *(const bf16x8*)(Er + (size_t)l2 * DHEAD + q * 8);
    e.e21 = *(const bf16x8*)(Er + (size_t)l2 * DHEAD + 32 + q * 8);
  };

  stage(0, 0);
  bf16x8 qf0 = *(const bf16x8*)(qbh + (size_t)(s0 + r) * DHEAD + q * 8);
  bf16x8 qf1 = *(const bf16x8*)(qbh + (size_t)(s0 + r) * DHEAD + 32 + q * 8);

  f32x4 oacc[4] = {};
  float lpart[4] = {0.f, 0.f, 0.f, 0.f};
  f32x4 qer0;
  {                                             // window init tile (cols 0..15)
    const int l0 = 2032 - s0 + r;               // in [r, 2032+r] always valid
    bf16x8 e00 = *(const bf16x8*)(Er + (size_t)l0 * DHEAD + q * 8);
    bf16x8 e01 = *(const bf16x8*)(Er + (size_t)l0 * DHEAD + 32 + q * 8);
    qer0 = MFMA(qf1, e01, MFMA(qf0, e00, zero4));
  }

  auto body = [&](int it, int cur, const ErF& e) {
    const int t0 = it * 32;
    if (t0 > s0 + 15) return;                   // tail-inactive wave (no barriers inside)
    const unsigned short* KL = &k_lds[cur][0];
    const unsigned short* VL = &v_lds[cur][0];
    bf16x8 kf00 = *(const bf16x8*)(KL + lane * 8);          // (ct0,kc0)
    bf16x8 kf10 = *(const bf16x8*)(KL + 512 + lane * 8);    // (ct1,kc0)
    bf16x8 kf01 = *(const bf16x8*)(KL + 1024 + lane * 8);   // (ct0,kc1)
    bf16x8 kf11 = *(const bf16x8*)(KL + 1536 + lane * 8);   // (ct1,kc1)

    __builtin_amdgcn_s_setprio(1);
    f32x4 s40  = MFMA(qf1, kf01, MFMA(qf0, kf00, zero4));
    f32x4 s41  = MFMA(qf1, kf11, MFMA(qf0, kf10, zero4));
    f32x4 qer1 = MFMA(qf1, e.e11, MFMA(qf0, e.e10, zero4));
    f32x4 qer2 = MFMA(qf1, e.e21, MFMA(qf0, e.e20, zero4));
    __builtin_amdgcn_s_setprio(0);

    const int d0 = t0 - s0;
#pragma unroll
    for (int j = 0; j < 4; ++j) {
      const int sl = q * 4 + j;
      const int idxw = r + 15 - sl;             // window col for ct=0 (0..30)
      const int srcl = (q << 4) | (idxw & 15);
      const float g0s = __shfl(qer0[j], srcl);
      const float g1s = __shfl(qer1[j], srcl);
      const float g2s = __shfl(qer2[j], srcl);
      const bool lo = (idxw < 16);
      const float sv0 = s40[j] + (lo ? g0s : g1s);   // Q pre-scaled by 1/8
      const float sv1 = s41[j] + (lo ? g1s : g2s);
      const int a = sl - r;                     // unmasked iff a >= d0 (+16)
      const float p0 = (a >= d0)      ? __expf(sv0) : 0.f;
      const float p1 = (a >= d0 + 16) ? __expf(sv1) : 0.f;
      lpart[j] += p0 + p1;
      p_lds[wv][sl][r]      = f2bf(p0);
      p_lds[wv][sl][16 + r] = f2bf(p1);
    }

    bf16x8 pf  = *(const bf16x8*)(&p_lds[wv][r][0] + q * 8);
    bf16x8 vf0 = *(const bf16x8*)(VL + lane * 8);
    bf16x8 vf1 = *(const bf16x8*)(VL + 512 + lane * 8);
    bf16x8 vf2 = *(const bf16x8*)(VL + 1024 + lane * 8);
    bf16x8 vf3 = *(const bf16x8*)(VL + 1536 + lane * 8);
    __builtin_amdgcn_s_setprio(1);
    oacc[0] = MFMA(pf, vf0, oacc[0]);
    oacc[1] = MFMA(pf, vf1, oacc[1]);
    oacc[2] = MFMA(pf, vf2, oacc[2]);
    oacc[3] = MFMA(pf, vf3, oacc[3]);
    __builtin_amdgcn_s_setprio(0);
    qer0 = qer2;                                // slide lattice window
  };

  ErF eA, eB;
  loadE(eA, 0);
  int it = 0;
  while (true) {                                // 2x unrolled ping-pong (no reg moves)
    __syncthreads();                            // buf0 staged
    if (it + 1 < nIter) { stage(it + 1, 1); loadE(eB, it + 1); }
    body(it, 0, eA);
    if (++it >= nIter) break;
    __syncthreads();                            // buf1 staged
    if (it + 1 < nIter) { stage(it + 1, 0); loadE(eA, it + 1); }
    body(it, 1, eB);
    if (++it >= nIter) break;
  }

  // epilogue: per-row denominator reduce, normalize, direct fp32 store
#pragma unroll
  for (int j = 0; j < 4; ++j) {
    float ls = lpart[j];
#pragma unroll
    for (int d = 1; d < 16; d <<= 1) ls += __shfl_xor(ls, d);
    const float inv = 1.0f / ls;
    const int ss = s0 + q * 4 + j;
#pragma unroll
    for (int dc = 0; dc < 4; ++dc) {
      const int dd = dc * 16 + r;
      out[((size_t)(bb * SEQ_ + ss)) * DMODEL + hh * DHEAD + dd] = oacc[dc][j] * inv;
    }
  }
}

// ------------------------------------------------------------------ launch ---
extern "C" void kernel_launch(void* const* d_in, const int* in_sizes, int n_in,
                              void* d_out, int out_size, void* d_ws, size_t ws_size,
                              hipStream_t stream) {
  const float* query = (const float*)d_in[0];
  const float* key   = (const float*)d_in[1];
  const float* value = (const float*)d_in[2];
  const float* Wq    = (const float*)d_in[3];
  const float* bq    = (const float*)d_in[4];
  const float* Wk    = (const float*)d_in[5];
  const float* bk    = (const float*)d_in[6];
  const float* Wv    = (const float*)d_in[7];
  const float* bv    = (const float*)d_in[8];
  const float* Er    = (const float*)d_in[9];

  char* ws = (char*)d_ws;
  unsigned short* qb   = (unsigned short*)(ws + (0u  << 20));  // (B,H,S,64) bf16  8MB
  unsigned short* ktil = (unsigned short*)(ws + (8u  << 20));  // K frag-tiles     8MB
  unsigned short* vtil = (unsigned short*)(ws + (16u << 20));  // V frag-tiles     8MB
  unsigned short* Xq   = (unsigned short*)(ws + (32u << 20));  // (B*S, D) bf16    8MB
  unsigned short* Xk   = (unsigned short*)(ws + (40u << 20));
  unsigned short* Xv   = (unsigned short*)(ws + (48u << 20));
  unsigned short* Wqb  = (unsigned short*)(ws + (56u << 20));  // (D, D) bf16      2MB
  unsigned short* Wkb  = (unsigned short*)(ws + (58u << 20));
  unsigned short* Wvb  = (unsigned short*)(ws + (60u << 20));
  unsigned short* Erb  = (unsigned short*)(ws + (62u << 20));  // (2048, 64)     256KB

  conv3_kernel<<<dim3(2048, 3), 256, 0, stream>>>(query, key, value, Xq, Xk, Xv,
                                                  2 * SEQ_ * DMODEL);
  conv4_kernel<<<dim3(512, 4), 256, 0, stream>>>(Wq, Wk, Wv, Er,
                                                 Wqb, Wkb, Wvb, Erb,
                                                 DMODEL * DMODEL, SEQ_ * DHEAD);

  proj3_kernel<<<dim3(32, 8, 3), 256, 0, stream>>>(Xq, Xk, Xv, Wqb, Wkb, Wvb,
                                                   bq, bk, bv, qb, ktil, vtil);

  attn_kernel<<<dim3(512), 512, 0, stream>>>(qb, ktil, vtil, Erb, (float*)d_out);
}

// Round 9
// 144.502 us; speedup vs baseline: 1.1338x; 1.1338x over previous
//
#include <hip/hip_runtime.h>
#include <hip/hip_bf16.h>

typedef __attribute__((ext_vector_type(8))) short bf16x8;   // 8 bf16 = 4 VGPR (MFMA A/B frag)
typedef __attribute__((ext_vector_type(4))) float f32x4;    // MFMA C/D frag

#define DEVI __device__ __forceinline__
#define AS1 __attribute__((address_space(1)))
#define AS3 __attribute__((address_space(3)))

constexpr int SEQ_   = 2048;
constexpr int HEADS  = 16;
constexpr int DHEAD  = 64;
constexpr int DMODEL = 1024;

DEVI unsigned short f2bf(float x) {
  __hip_bfloat16 h = __float2bfloat16(x);   // RNE
  return __builtin_bit_cast(unsigned short, h);
}

DEVI f32x4 MFMA(bf16x8 a, bf16x8 b, f32x4 c) {
  return __builtin_amdgcn_mfma_f32_16x16x32_bf16(a, b, c, 0, 0, 0);
}

// ---------------------------------------------------------------- convert ---
__global__ void conv3_kernel(const float* s0, const float* s1, const float* s2,
                             unsigned short* d0, unsigned short* d1, unsigned short* d2,
                             int n) {
  const float* s = (blockIdx.y == 0) ? s0 : (blockIdx.y == 1) ? s1 : s2;
  unsigned short* d = (blockIdx.y == 0) ? d0 : (blockIdx.y == 1) ? d1 : d2;
  int i = (blockIdx.x * 256 + threadIdx.x) * 8;
  if (i >= n) return;
  const float4* p = (const float4*)(s + i);
  float4 v0 = p[0], v1 = p[1];
  union { unsigned short u[8]; bf16x8 v; } t;
  t.u[0] = f2bf(v0.x); t.u[1] = f2bf(v0.y); t.u[2] = f2bf(v0.z); t.u[3] = f2bf(v0.w);
  t.u[4] = f2bf(v1.x); t.u[5] = f2bf(v1.y); t.u[6] = f2bf(v1.z); t.u[7] = f2bf(v1.w);
  *(bf16x8*)(d + i) = t.v;
}

// weights (y=0..2, n_w elems) + Er (y=3, n_e elems) in one launch
__global__ void conv4_kernel(const float* s0, const float* s1, const float* s2,
                             const float* s3,
                             unsigned short* d0, unsigned short* d1,
                             unsigned short* d2, unsigned short* d3,
                             int n_w, int n_e) {
  const int y = blockIdx.y;
  const float* s = (y == 0) ? s0 : (y == 1) ? s1 : (y == 2) ? s2 : s3;
  unsigned short* d = (y == 0) ? d0 : (y == 1) ? d1 : (y == 2) ? d2 : d3;
  const int n = (y == 3) ? n_e : n_w;
  int i = (blockIdx.x * 256 + threadIdx.x) * 8;
  if (i >= n) return;
  const float4* p = (const float4*)(s + i);
  float4 v0 = p[0], v1 = p[1];
  union { unsigned short u[8]; bf16x8 v; } t;
  t.u[0] = f2bf(v0.x); t.u[1] = f2bf(v0.y); t.u[2] = f2bf(v0.z); t.u[3] = f2bf(v0.w);
  t.u[4] = f2bf(v1.x); t.u[5] = f2bf(v1.y); t.u[6] = f2bf(v1.z); t.u[7] = f2bf(v1.w);
  *(bf16x8*)(d + i) = t.v;
}

// ------------------------------------------------------------- projection ---
// z==0 (Q): out (b,h,s,d), PRE-SCALED by 0.125 (folds the 1/sqrt(dh)).
// z==1 (K): 4KB tiles (per 32 t) in MFMA fragment order.
// z==2 (V): 4KB tiles (per 32 t) in MFMA fragment order.
__global__ __launch_bounds__(256) void proj3_kernel(
    const unsigned short* __restrict__ X0, const unsigned short* __restrict__ X1,
    const unsigned short* __restrict__ X2,
    const unsigned short* __restrict__ W0, const unsigned short* __restrict__ W1,
    const unsigned short* __restrict__ W2,
    const float* __restrict__ bi0, const float* __restrict__ bi1,
    const float* __restrict__ bi2,
    unsigned short* __restrict__ o0, unsigned short* __restrict__ o1,
    unsigned short* __restrict__ o2) {
  const int z = blockIdx.z;
  const unsigned short* X = (z == 0) ? X0 : (z == 1) ? X1 : X2;
  const unsigned short* W = (z == 0) ? W0 : (z == 1) ? W1 : W2;
  const float* bias        = (z == 0) ? bi0 : (z == 1) ? bi1 : bi2;
  unsigned short* out      = (z == 0) ? o0 : (z == 1) ? o1 : o2;

  __shared__ unsigned short Abuf[2][128 * 32];
  __shared__ unsigned short Bbuf[2][128 * 32];
  const int tid  = threadIdx.x;
  const int lane = tid & 63, wv = tid >> 6;
  const int q = lane >> 4, r = lane & 15;
  const int wrow = wv >> 1, wcol = wv & 1;
  const int rowA0 = blockIdx.x * 128, colB0 = blockIdx.y * 128;

  const char* Ag = (const char*)(X + (size_t)rowA0 * DMODEL);
  const char* Bg = (const char*)(W + (size_t)colB0 * DMODEL);

  f32x4 acc[4][4] = {};

  auto stage = [&](int ks, int buf) {
    const int koff = ks * 64;
#pragma unroll
    for (int i = 0; i < 2; ++i) {
      const int b   = (i * 256 + tid) * 16;
      const int row = b >> 6, col = b & 63;
      __builtin_amdgcn_global_load_lds(
          (const AS1 void*)(Ag + (size_t)row * (DMODEL * 2) + koff + col),
          (AS3 void*)((char*)&Abuf[buf][0] + i * 4096 + wv * 1024),
          16, 0, 0);
      __builtin_amdgcn_global_load_lds(
          (const AS1 void*)(Bg + (size_t)row * (DMODEL * 2) + koff + col),
          (AS3 void*)((char*)&Bbuf[buf][0] + i * 4096 + wv * 1024),
          16, 0, 0);
    }
  };

  stage(0, 0);
  for (int ks = 0; ks < 32; ++ks) {
    __syncthreads();
    if (ks + 1 < 32) stage(ks + 1, (ks + 1) & 1);
    const unsigned short* A  = &Abuf[ks & 1][0];
    const unsigned short* Bt = &Bbuf[ks & 1][0];
    bf16x8 af[4], bfr[4];
#pragma unroll
    for (int t = 0; t < 4; ++t) {
      af[t]  = *(const bf16x8*)(A  + (wrow * 64 + t * 16 + r) * 32 + q * 8);
      bfr[t] = *(const bf16x8*)(Bt + (wcol * 64 + t * 16 + r) * 32 + q * 8);
    }
#pragma unroll
    for (int m = 0; m < 4; ++m)
#pragma unroll
      for (int n = 0; n < 4; ++n)
        acc[m][n] = MFMA(af[m], bfr[n], acc[m][n]);
  }

#pragma unroll
  for (int m = 0; m < 4; ++m) {
#pragma unroll
    for (int n = 0; n < 4; ++n) {
      const int e  = colB0 + wcol * 64 + n * 16 + r;
      const float bv = bias[e];
      const int h = e >> 6, dd = e & 63;
      const int nrow0 = rowA0 + wrow * 64 + m * 16 + q * 4;
      const int bb = nrow0 >> 11, ss0 = nrow0 & 2047;
      const size_t bh = (size_t)(bb * HEADS + h);
      if (z == 0) {
#pragma unroll
        for (int j = 0; j < 4; ++j)
          out[(bh * SEQ_ + (ss0 + j)) * DHEAD + dd] = f2bf((acc[m][n][j] + bv) * 0.125f);
      } else if (z == 1) {
#pragma unroll
        for (int j = 0; j < 4; ++j) {
          const int s = ss0 + j;
          const size_t off = (bh * 64 + (size_t)(s >> 5)) * 2048
                           + (size_t)(((dd >> 5) * 2 + ((s >> 4) & 1)) * 512)
                           + (size_t)(((((dd & 31) >> 3) << 4) + (s & 15)) * 8)
                           + (dd & 7);
          out[off] = f2bf(acc[m][n][j] + bv);
        }
      } else {
        union { unsigned short u[4]; uint2 v; } pk;
#pragma unroll
        for (int j = 0; j < 4; ++j) pk.u[j] = f2bf(acc[m][n][j] + bv);
        const size_t off = (bh * 64 + (size_t)(ss0 >> 5)) * 2048
                         + (size_t)((dd >> 4) * 512)
                         + (size_t)(((((ss0 & 31) >> 3) << 4) + (dd & 15)) * 8)
                         + (ss0 & 7);
        *(uint2*)&out[off] = pk.v;
      }
    }
  }
}

// -------------------------------------------------------------- attention ---
// 512 blocks x 256 thr (4 waves x 32 rows = 128-row tile/block, 2 blocks/CU).
// KVBLK=64 (2 frag-tiles staged per iter = 16KB), 3-buffer LDS ring, raw
// s_barrier + COUNTED s_waitcnt vmcnt(12): each iter issues exactly 12 vmem
// ops/wave (4 stage DMA + 8 Er frag loads, tail-clamped) BEFORE the wait, so
// the wait only drains ops >= 1 iter old — current stage stays in flight
// across the barrier (T3/T4; kills the R5-R8 vmcnt(0) barrier drain).
// QEr: 6-tile x 2rt sliding lattice, carry 2/rt, fresh 4/rt per iter; gather
// = 5 shfl + lane-static hi-select per (rt,j). Fixed-max softmax.
__global__ __launch_bounds__(256, 2) void attn_kernel(
    const unsigned short* __restrict__ qb, const unsigned short* __restrict__ kt,
    const unsigned short* __restrict__ vt, const unsigned short* __restrict__ Er,
    float* __restrict__ out) {
  __shared__ unsigned short k_lds[3][4096];     // 8KB/buf: 2 frag-tiles
  __shared__ unsigned short v_lds[3][4096];
  __shared__ unsigned short p_lds[4][32][72];   // per-wave P (32x64 + pad)

  const int tid  = threadIdx.x;
  const int lane = tid & 63, wv = tid >> 6;     // 4 waves
  const int q = lane >> 4, r = lane & 15;

  const int lid = blockIdx.x;
  const int xcd = lid & 7, idx = lid >> 3;      // 64 per XCD
  const int bh  = (xcd << 2) | (idx & 3);       // 4 bh pinned per XCD L2
  const int T   = 15 - (idx >> 2);              // big tiles dispatched first
  const int s0  = T * 128 + wv * 32;            // this wave's 32 rows
  const int nIter = 2 * T + 2;
  const int bb = bh >> 4, hh = bh & 15;

  const unsigned short* qbh = qb + (size_t)bh * SEQ_ * DHEAD;
  const char* ktb = (const char*)(kt + (size_t)bh * 64 * 2048);
  const char* vtb = (const char*)(vt + (size_t)bh * 64 * 2048);
  const f32x4 zero4 = {0.f, 0.f, 0.f, 0.f};

  // ---- staging: waves 0,1 -> K, waves 2,3 -> V; 4 x 1KB DMA per wave ----
  const char* sgbase = (wv < 2) ? ktb : vtb;
  char* sdst0 = (char*)((wv < 2) ? &k_lds[0][0] : &v_lds[0][0]);
  const int shalf = (wv & 1) * 4096;
  const int soff  = lane * 16;

  auto stageKV = [&](int it, int buf) {
    const int g = (it < nIter) ? it : nIter - 1;    // clamp: constant op count
    const char* src = sgbase + (size_t)g * 8192 + shalf + soff;
    char* dst = sdst0 + buf * 8192 + shalf;
#pragma unroll
    for (int c = 0; c < 4; ++c)
      __builtin_amdgcn_global_load_lds((const AS1 void*)(src + c * 1024),
                                       (AS3 void*)(dst + c * 1024), 16, 0, 0);
  };

  // ---- Er fragment loads for iter's 4 fresh lattice tiles (m=2..5) ----
  struct ErSet { bf16x8 e[8]; };                // [mi*2 + kc], const-indexed
  auto loadE = [&](ErSet& es, int it) {
    const int lb = 2016 + it * 64 - s0;
#pragma unroll
    for (int mi = 0; mi < 4; ++mi) {
      int l = lb + 32 + mi * 16 + r;
      l = l < 2047 ? l : 2047;                  // clamped rows feed masked cols
      es.e[mi * 2 + 0] = *(const bf16x8*)(Er + (size_t)l * DHEAD + q * 8);
      es.e[mi * 2 + 1] = *(const bf16x8*)(Er + (size_t)l * DHEAD + 32 + q * 8);
    }
  };

  // ---- prologue ----
  bf16x8 qf[2][2];
#pragma unroll
  for (int rt = 0; rt < 2; ++rt) {
    qf[rt][0] = *(const bf16x8*)(qbh + (size_t)(s0 + rt * 16 + r) * DHEAD + q * 8);
    qf[rt][1] = *(const bf16x8*)(qbh + (size_t)(s0 + rt * 16 + r) * DHEAD + 32 + q * 8);
  }
  stageKV(0, 0);

  f32x4 qer[2][6];                              // lattice (const-indexed after unroll)
  {                                             // init tiles m=0,1 (iter 0)
    const int lb = 2016 - s0;
#pragma unroll
    for (int m = 0; m < 2; ++m) {
      const int l = lb + m * 16 + r;            // always in [0,2047]
      bf16x8 e0 = *(const bf16x8*)(Er + (size_t)l * DHEAD + q * 8);
      bf16x8 e1 = *(const bf16x8*)(Er + (size_t)l * DHEAD + 32 + q * 8);
#pragma unroll
      for (int rt = 0; rt < 2; ++rt)
        qer[rt][m] = MFMA(qf[rt][1], e1, MFMA(qf[rt][0], e0, zero4));
    }
  }

  f32x4 oacc[2][4] = {};
  float lpart[2][4] = {};

  ErSet eA, eB;
  loadE(eA, 0);

  // ---- body ----
  auto body = [&](int it, int cur, const ErSet& es) {
    const int t0 = it * 64;
    if (t0 > s0 + 31) return;                   // tail-inactive (wave-uniform)
    const unsigned short* KL = &k_lds[cur][0];
    const unsigned short* VL = &v_lds[cur][0];

    bf16x8 kf[4][2];
#pragma unroll
    for (int ct = 0; ct < 4; ++ct)
#pragma unroll
      for (int kc = 0; kc < 2; ++kc)
        kf[ct][kc] = *(const bf16x8*)(KL + (ct >> 1) * 2048 + (kc * 2 + (ct & 1)) * 512 + lane * 8);

    f32x4 s4[2][4];
    __builtin_amdgcn_s_setprio(1);
#pragma unroll
    for (int rt = 0; rt < 2; ++rt)
#pragma unroll
      for (int ct = 0; ct < 4; ++ct)
        s4[rt][ct] = MFMA(qf[rt][1], kf[ct][1], MFMA(qf[rt][0], kf[ct][0], zero4));
#pragma unroll
    for (int rt = 0; rt < 2; ++rt)
#pragma unroll
      for (int mi = 0; mi < 4; ++mi)
        qer[rt][2 + mi] = MFMA(qf[rt][1], es.e[mi * 2 + 1],
                               MFMA(qf[rt][0], es.e[mi * 2 + 0], zero4));
    __builtin_amdgcn_s_setprio(0);

    const int d0 = t0 - s0;
#pragma unroll
    for (int rt = 0; rt < 2; ++rt) {
#pragma unroll
      for (int j = 0; j < 4; ++j) {
        const int srcl = (q << 4) | ((15 + r - q * 4 - j) & 15);
        // lattice tiles needed: rt0 -> 1..5, rt1 -> 0..4
        float g0 = __shfl(qer[rt][1 - rt][j], srcl);
        float g1 = __shfl(qer[rt][2 - rt][j], srcl);
        float g2 = __shfl(qer[rt][3 - rt][j], srcl);
        float g3 = __shfl(qer[rt][4 - rt][j], srcl);
        float g4 = __shfl(qer[rt][5 - rt][j], srcl);
        const bool hi = (r > q * 4 + j);        // lane-static select
        const float b0 = hi ? g1 : g0;
        const float b1 = hi ? g2 : g1;
        const float b2 = hi ? g3 : g2;
        const float b3 = hi ? g4 : g3;
        const int A_ = rt * 16 + q * 4 + j - r - d0;   // keep iff ct*16 <= A_
        const float p0 = (A_ >= 0)  ? __expf(s4[rt][0][j] + b0) : 0.f;
        const float p1 = (A_ >= 16) ? __expf(s4[rt][1][j] + b1) : 0.f;
        const float p2 = (A_ >= 32) ? __expf(s4[rt][2][j] + b2) : 0.f;
        const float p3 = (A_ >= 48) ? __expf(s4[rt][3][j] + b3) : 0.f;
        lpart[rt][j] += (p0 + p1) + (p2 + p3);
        const int sl = rt * 16 + q * 4 + j;
        p_lds[wv][sl][r]      = f2bf(p0);
        p_lds[wv][sl][16 + r] = f2bf(p1);
        p_lds[wv][sl][32 + r] = f2bf(p2);
        p_lds[wv][sl][48 + r] = f2bf(p3);
      }
    }

    bf16x8 vf[4][2];
#pragma unroll
    for (int dc = 0; dc < 4; ++dc)
#pragma unroll
      for (int tc = 0; tc < 2; ++tc)
        vf[dc][tc] = *(const bf16x8*)(VL + tc * 2048 + dc * 512 + lane * 8);
    __builtin_amdgcn_s_setprio(1);
#pragma unroll
    for (int rt = 0; rt < 2; ++rt) {
      bf16x8 pf0 = *(const bf16x8*)(&p_lds[wv][rt * 16 + r][0] + q * 8);
      bf16x8 pf1 = *(const bf16x8*)(&p_lds[wv][rt * 16 + r][0] + 32 + q * 8);
#pragma unroll
      for (int dc = 0; dc < 4; ++dc)
        oacc[rt][dc] = MFMA(pf1, vf[dc][1], MFMA(pf0, vf[dc][0], oacc[rt][dc]));
    }
    __builtin_amdgcn_s_setprio(0);

    // slide lattice window (+64 cols)
#pragma unroll
    for (int rt = 0; rt < 2; ++rt) { qer[rt][0] = qer[rt][4]; qer[rt][1] = qer[rt][5]; }
  };

  // ---- main loop: counted-vmcnt ring (exactly 12 vmem ops/wave/iter) ----
  int it = 0, cur = 0;
  while (true) {
    int nxt = cur + 1; if (nxt == 3) nxt = 0;
    stageKV(it + 1, nxt);
    loadE(eB, it + 1);
    asm volatile("s_waitcnt vmcnt(12)\n\ts_barrier" ::: "memory");
    body(it, cur, eA);
    cur = nxt;
    if (++it >= nIter) break;
    nxt = cur + 1; if (nxt == 3) nxt = 0;
    stageKV(it + 1, nxt);
    loadE(eA, it + 1);
    asm volatile("s_waitcnt vmcnt(12)\n\ts_barrier" ::: "memory");
    body(it, cur, eB);
    cur = nxt;
    if (++it >= nIter) break;
  }

  // ---- epilogue: denominator reduce, normalize, direct fp32 store ----
#pragma unroll
  for (int rt = 0; rt < 2; ++rt)
#pragma unroll
    for (int j = 0; j < 4; ++j) {
      float ls = lpart[rt][j];
#pragma unroll
      for (int d = 1; d < 16; d <<= 1) ls += __shfl_xor(ls, d);
      const float inv = 1.0f / ls;
      const int ss = s0 + rt * 16 + q * 4 + j;
#pragma unroll
      for (int dc = 0; dc < 4; ++dc) {
        const int dd = dc * 16 + r;
        out[((size_t)(bb * SEQ_ + ss)) * DMODEL + hh * DHEAD + dd] = oacc[rt][dc][j] * inv;
      }
    }
}

// ------------------------------------------------------------------ launch ---
extern "C" void kernel_launch(void* const* d_in, const int* in_sizes, int n_in,
                              void* d_out, int out_size, void* d_ws, size_t ws_size,
                              hipStream_t stream) {
  const float* query = (const float*)d_in[0];
  const float* key   = (const float*)d_in[1];
  const float* value = (const float*)d_in[2];
  const float* Wq    = (const float*)d_in[3];
  const float* bq    = (const float*)d_in[4];
  const float* Wk    = (const float*)d_in[5];
  const float* bk    = (const float*)d_in[6];
  const float* Wv    = (const float*)d_in[7];
  const float* bv    = (const float*)d_in[8];
  const float* Er    = (const float*)d_in[9];

  char* ws = (char*)d_ws;
  unsigned short* qb   = (unsigned short*)(ws + (0u  << 20));  // (B,H,S,64) bf16  8MB
  unsigned short* ktil = (unsigned short*)(ws + (8u  << 20));  // K frag-tiles     8MB
  unsigned short* vtil = (unsigned short*)(ws + (16u << 20));  // V frag-tiles     8MB
  unsigned short* Xq   = (unsigned short*)(ws + (32u << 20));  // (B*S, D) bf16    8MB
  unsigned short* Xk   = (unsigned short*)(ws + (40u << 20));
  unsigned short* Xv   = (unsigned short*)(ws + (48u << 20));
  unsigned short* Wqb  = (unsigned short*)(ws + (56u << 20));  // (D, D) bf16      2MB
  unsigned short* Wkb  = (unsigned short*)(ws + (58u << 20));
  unsigned short* Wvb  = (unsigned short*)(ws + (60u << 20));
  unsigned short* Erb  = (unsigned short*)(ws + (62u << 20));  // (2048, 64)     256KB

  conv3_kernel<<<dim3(2048, 3), 256, 0, stream>>>(query, key, value, Xq, Xk, Xv,
                                                  2 * SEQ_ * DMODEL);
  conv4_kernel<<<dim3(512, 4), 256, 0, stream>>>(Wq, Wk, Wv, Er,
                                                 Wqb, Wkb, Wvb, Erb,
                                                 DMODEL * DMODEL, SEQ_ * DHEAD);

  proj3_kernel<<<dim3(32, 8, 3), 256, 0, stream>>>(Xq, Xk, Xv, Wqb, Wkb, Wvb,
                                                   bq, bk, bv, qb, ktil, vtil);

  attn_kernel<<<dim3(512), 256, 0, stream>>>(qb, ktil, vtil, Erb, (float*)d_out);
}

// Round 10
// 141.275 us; speedup vs baseline: 1.1597x; 1.0228x over previous
//
#include <hip/hip_runtime.h>
#include <hip/hip_bf16.h>

typedef __attribute__((ext_vector_type(8))) short bf16x8;   // 8 bf16 = 4 VGPR (MFMA A/B frag)
typedef __attribute__((ext_vector_type(4))) float f32x4;    // MFMA C/D frag

#define DEVI __device__ __forceinline__
#define AS1 __attribute__((address_space(1)))
#define AS3 __attribute__((address_space(3)))

constexpr int SEQ_   = 2048;
constexpr int HEADS  = 16;
constexpr int DHEAD  = 64;
constexpr int DMODEL = 1024;

DEVI unsigned short f2bf(float x) {
  __hip_bfloat16 h = __float2bfloat16(x);   // RNE
  return __builtin_bit_cast(unsigned short, h);
}

DEVI f32x4 MFMA(bf16x8 a, bf16x8 b, f32x4 c) {
  return __builtin_amdgcn_mfma_f32_16x16x32_bf16(a, b, c, 0, 0, 0);
}

DEVI unsigned int cvtpk(float lo, float hi) {   // dst.lo16 = bf16(lo), dst.hi16 = bf16(hi)
  unsigned int u;
  asm("v_cvt_pk_bf16_f32 %0, %1, %2" : "=v"(u) : "v"(lo), "v"(hi));
  return u;
}

// ---------------------------------------------------------------- convert ---
__global__ void conv3_kernel(const float* s0, const float* s1, const float* s2,
                             unsigned short* d0, unsigned short* d1, unsigned short* d2,
                             int n) {
  const float* s = (blockIdx.y == 0) ? s0 : (blockIdx.y == 1) ? s1 : s2;
  unsigned short* d = (blockIdx.y == 0) ? d0 : (blockIdx.y == 1) ? d1 : d2;
  int i = (blockIdx.x * 256 + threadIdx.x) * 8;
  if (i >= n) return;
  const float4* p = (const float4*)(s + i);
  float4 v0 = p[0], v1 = p[1];
  union { unsigned short u[8]; bf16x8 v; } t;
  t.u[0] = f2bf(v0.x); t.u[1] = f2bf(v0.y); t.u[2] = f2bf(v0.z); t.u[3] = f2bf(v0.w);
  t.u[4] = f2bf(v1.x); t.u[5] = f2bf(v1.y); t.u[6] = f2bf(v1.z); t.u[7] = f2bf(v1.w);
  *(bf16x8*)(d + i) = t.v;
}

__global__ void conv4_kernel(const float* s0, const float* s1, const float* s2,
                             const float* s3,
                             unsigned short* d0, unsigned short* d1,
                             unsigned short* d2, unsigned short* d3,
                             int n_w, int n_e) {
  const int y = blockIdx.y;
  const float* s = (y == 0) ? s0 : (y == 1) ? s1 : (y == 2) ? s2 : s3;
  unsigned short* d = (y == 0) ? d0 : (y == 1) ? d1 : (y == 2) ? d2 : d3;
  const int n = (y == 3) ? n_e : n_w;
  int i = (blockIdx.x * 256 + threadIdx.x) * 8;
  if (i >= n) return;
  const float4* p = (const float4*)(s + i);
  float4 v0 = p[0], v1 = p[1];
  union { unsigned short u[8]; bf16x8 v; } t;
  t.u[0] = f2bf(v0.x); t.u[1] = f2bf(v0.y); t.u[2] = f2bf(v0.z); t.u[3] = f2bf(v0.w);
  t.u[4] = f2bf(v1.x); t.u[5] = f2bf(v1.y); t.u[6] = f2bf(v1.z); t.u[7] = f2bf(v1.w);
  *(bf16x8*)(d + i) = t.v;
}

// ------------------------------------------------------------- projection ---
// z==0 (Q): out (b,h,s,d), pre-scaled by 0.125.
// z==1 (K): 4KB tiles (per 32 t) in MFMA fragment order.
// z==2 (V): 8KB tiles (per 64 t) frag order with t' = 4*(t&15) + (t>>4)
//           permutation (matches attn's b64 P-write order).
__global__ __launch_bounds__(256) void proj3_kernel(
    const unsigned short* __restrict__ X0, const unsigned short* __restrict__ X1,
    const unsigned short* __restrict__ X2,
    const unsigned short* __restrict__ W0, const unsigned short* __restrict__ W1,
    const unsigned short* __restrict__ W2,
    const float* __restrict__ bi0, const float* __restrict__ bi1,
    const float* __restrict__ bi2,
    unsigned short* __restrict__ o0, unsigned short* __restrict__ o1,
    unsigned short* __restrict__ o2) {
  const int z = blockIdx.z;
  const unsigned short* X = (z == 0) ? X0 : (z == 1) ? X1 : X2;
  const unsigned short* W = (z == 0) ? W0 : (z == 1) ? W1 : W2;
  const float* bias        = (z == 0) ? bi0 : (z == 1) ? bi1 : bi2;
  unsigned short* out      = (z == 0) ? o0 : (z == 1) ? o1 : o2;

  __shared__ unsigned short Abuf[2][128 * 32];
  __shared__ unsigned short Bbuf[2][128 * 32];
  const int tid  = threadIdx.x;
  const int lane = tid & 63, wv = tid >> 6;
  const int q = lane >> 4, r = lane & 15;
  const int wrow = wv >> 1, wcol = wv & 1;
  const int rowA0 = blockIdx.x * 128, colB0 = blockIdx.y * 128;

  const char* Ag = (const char*)(X + (size_t)rowA0 * DMODEL);
  const char* Bg = (const char*)(W + (size_t)colB0 * DMODEL);

  f32x4 acc[4][4] = {};

  auto stage = [&](int ks, int buf) {
    const int koff = ks * 64;
#pragma unroll
    for (int i = 0; i < 2; ++i) {
      const int b   = (i * 256 + tid) * 16;
      const int row = b >> 6, col = b & 63;
      __builtin_amdgcn_global_load_lds(
          (const AS1 void*)(Ag + (size_t)row * (DMODEL * 2) + koff + col),
          (AS3 void*)((char*)&Abuf[buf][0] + i * 4096 + wv * 1024),
          16, 0, 0);
      __builtin_amdgcn_global_load_lds(
          (const AS1 void*)(Bg + (size_t)row * (DMODEL * 2) + koff + col),
          (AS3 void*)((char*)&Bbuf[buf][0] + i * 4096 + wv * 1024),
          16, 0, 0);
    }
  };

  stage(0, 0);
  for (int ks = 0; ks < 32; ++ks) {
    __syncthreads();
    if (ks + 1 < 32) stage(ks + 1, (ks + 1) & 1);
    const unsigned short* A  = &Abuf[ks & 1][0];
    const unsigned short* Bt = &Bbuf[ks & 1][0];
    bf16x8 af[4], bfr[4];
#pragma unroll
    for (int t = 0; t < 4; ++t) {
      af[t]  = *(const bf16x8*)(A  + (wrow * 64 + t * 16 + r) * 32 + q * 8);
      bfr[t] = *(const bf16x8*)(Bt + (wcol * 64 + t * 16 + r) * 32 + q * 8);
    }
#pragma unroll
    for (int m = 0; m < 4; ++m)
#pragma unroll
      for (int n = 0; n < 4; ++n)
        acc[m][n] = MFMA(af[m], bfr[n], acc[m][n]);
  }

#pragma unroll
  for (int m = 0; m < 4; ++m) {
#pragma unroll
    for (int n = 0; n < 4; ++n) {
      const int e  = colB0 + wcol * 64 + n * 16 + r;
      const float bv = bias[e];
      const int h = e >> 6, dd = e & 63;
      const int nrow0 = rowA0 + wrow * 64 + m * 16 + q * 4;
      const int bb = nrow0 >> 11, ss0 = nrow0 & 2047;
      const size_t bh = (size_t)(bb * HEADS + h);
      if (z == 0) {
#pragma unroll
        for (int j = 0; j < 4; ++j)
          out[(bh * SEQ_ + (ss0 + j)) * DHEAD + dd] = f2bf((acc[m][n][j] + bv) * 0.125f);
      } else if (z == 1) {
#pragma unroll
        for (int j = 0; j < 4; ++j) {
          const int s = ss0 + j;
          const size_t off = (bh * 64 + (size_t)(s >> 5)) * 2048
                           + (size_t)(((dd >> 5) * 2 + ((s >> 4) & 1)) * 512)
                           + (size_t)(((((dd & 31) >> 3) << 4) + (s & 15)) * 8)
                           + (dd & 7);
          out[off] = f2bf(acc[m][n][j] + bv);
        }
      } else {
        // V: 8KB tile per 64 t, t' = 4*(t&15) + (t>>4)
#pragma unroll
        for (int j = 0; j < 4; ++j) {
          const int s = ss0 + j;
          const int tile64 = s >> 6, t = s & 63;
          const int tp = 4 * (t & 15) + (t >> 4);
          const int tc = tp >> 5, u = tp & 31;
          const int ln = ((u >> 3) << 4) | (dd & 15);
          const size_t off = (bh * 32 + (size_t)tile64) * 4096
                           + (size_t)(tc * 2048 + (dd >> 4) * 512 + ln * 8 + (u & 7));
          out[off] = f2bf(acc[m][n][j] + bv);
        }
      }
    }
  }
}

// -------------------------------------------------------------- attention ---
// 512 blocks x 256 thr (4 waves x 32 rows = 128-row tile). Each block: exactly
// 17 contiguous iters = fh(T)=[0,T+1) of one tile + sh(15-T)=[T'+1,2T'+2) of
// its complement -> perfect balance, contiguous carry-lattice.
// LDS-pipe diet: packed-bf16 lattice gather (3 bperm vs 5), b64 P-write with
// t'-permuted V (8 writes vs 32). 3-ring + counted s_waitcnt vmcnt(12).
// fh writes unnormalized O to d_out + pL0; sh writes pO1 + pL1; reduce merges.
struct ErSet { bf16x8 e[8]; };

__global__ __launch_bounds__(256, 2) void attn_kernel(
    const unsigned short* __restrict__ qb, const unsigned short* __restrict__ kt,
    const unsigned short* __restrict__ vt, const unsigned short* __restrict__ Er,
    float* __restrict__ out, float* __restrict__ pO1, float* __restrict__ pL) {
  __shared__ unsigned short k_lds[3][4096];     // 8KB/buf (2x 4KB frag tiles)
  __shared__ unsigned short v_lds[3][4096];     // 8KB/buf (one 64-t permuted tile)
  __shared__ unsigned short p_lds[4][32][68];   // [s][t'] b64-written P

  const int tid  = threadIdx.x;
  const int lane = tid & 63, wv = tid >> 6;     // 4 waves
  const int q = lane >> 4, r = lane & 15;

  const int lid = blockIdx.x;
  const int xcd = lid & 7, idx = lid >> 3;
  const int bh  = (xcd << 2) | (idx & 3);       // 4 bh pinned per XCD L2
  const int jb  = idx >> 2;                     // 0..15
  const int p = jb >> 1, role = jb & 1;
  const int bb = bh >> 4, hh = bh & 15;

  const unsigned short* qbh = qb + (size_t)bh * SEQ_ * DHEAD;
  const char* ktb = (const char*)(kt + (size_t)bh * 64 * 2048);
  const char* vtb = (const char*)(vt + (size_t)bh * 32 * 4096);
  const f32x4 zero4 = {0.f, 0.f, 0.f, 0.f};

  const char* sgbase = (wv < 2) ? ktb : vtb;
  char* sdst0 = (char*)((wv < 2) ? &k_lds[0][0] : &v_lds[0][0]);
  const int shalf = (wv & 1) * 4096;
  const int soff  = lane * 16;

  auto stageKV = [&](int it, int buf) {         // 4 vmem ops, always
    const char* src = sgbase + (size_t)it * 8192 + shalf + soff;
    char* dst = sdst0 + buf * 8192 + shalf;
#pragma unroll
    for (int c = 0; c < 4; ++c)
      __builtin_amdgcn_global_load_lds((const AS1 void*)(src + c * 1024),
                                       (AS3 void*)(dst + c * 1024), 16, 0, 0);
  };

  // run one contiguous strip of tile T, iters [it0, it1)
  auto run_strip = [&](int T, int it0, int it1, float* po, float* pl) {
    const int s0 = T * 128 + wv * 32;
    __syncthreads();                            // drain prev strip (vmcnt->0 too)
    stageKV(it0, 0);

    bf16x8 qf[2][2];
#pragma unroll
    for (int rt = 0; rt < 2; ++rt) {
      qf[rt][0] = *(const bf16x8*)(qbh + (size_t)(s0 + rt * 16 + r) * DHEAD + q * 8);
      qf[rt][1] = *(const bf16x8*)(qbh + (size_t)(s0 + rt * 16 + r) * DHEAD + 32 + q * 8);
    }

    f32x4 qer[2][6];
    {                                           // lattice init: tiles 0,1
      const int lb0 = 2016 + it0 * 64 - s0;
#pragma unroll
      for (int m = 0; m < 2; ++m) {
        int l = lb0 + m * 16 + r; l = l < 2047 ? l : 2047;
        bf16x8 e0 = *(const bf16x8*)(Er + (size_t)l * DHEAD + q * 8);
        bf16x8 e1 = *(const bf16x8*)(Er + (size_t)l * DHEAD + 32 + q * 8);
#pragma unroll
        for (int rt = 0; rt < 2; ++rt)
          qer[rt][m] = MFMA(qf[rt][1], e1, MFMA(qf[rt][0], e0, zero4));
      }
    }

    auto loadE = [&](ErSet& es, int it) {       // 8 vmem ops, always
      const int lb = 2016 + it * 64 - s0;
#pragma unroll
      for (int mi = 0; mi < 4; ++mi) {
        int l = lb + 32 + mi * 16 + r;
        l = l < 2047 ? l : 2047;
        es.e[mi * 2 + 0] = *(const bf16x8*)(Er + (size_t)l * DHEAD + q * 8);
        es.e[mi * 2 + 1] = *(const bf16x8*)(Er + (size_t)l * DHEAD + 32 + q * 8);
      }
    };

    f32x4 oacc[2][4] = {};
    float lpart[2][4] = {};

    auto body = [&](int it, int cur, const ErSet& es) {
      const int t0 = it * 64;
      if (t0 > s0 + 31) return;                 // masked tail (no barriers inside)
      const unsigned short* KL = &k_lds[cur][0];
      const unsigned short* VL = &v_lds[cur][0];

      bf16x8 kf[4][2];
#pragma unroll
      for (int ct = 0; ct < 4; ++ct)
#pragma unroll
        for (int kc = 0; kc < 2; ++kc)
          kf[ct][kc] = *(const bf16x8*)(KL + (ct >> 1) * 2048 + (kc * 2 + (ct & 1)) * 512 + lane * 8);

      f32x4 s4[2][4];
      __builtin_amdgcn_s_setprio(1);
#pragma unroll
      for (int rt = 0; rt < 2; ++rt)
#pragma unroll
        for (int ct = 0; ct < 4; ++ct)
          s4[rt][ct] = MFMA(qf[rt][1], kf[ct][1], MFMA(qf[rt][0], kf[ct][0], zero4));
#pragma unroll
      for (int rt = 0; rt < 2; ++rt)
#pragma unroll
        for (int mi = 0; mi < 4; ++mi)
          qer[rt][2 + mi] = MFMA(qf[rt][1], es.e[mi * 2 + 1],
                                 MFMA(qf[rt][0], es.e[mi * 2 + 0], zero4));
      __builtin_amdgcn_s_setprio(0);

      const int d0 = t0 - s0;
#pragma unroll
      for (int rt = 0; rt < 2; ++rt) {
        const int a = 1 - rt;                   // lattice window base tile
#pragma unroll
        for (int j = 0; j < 4; ++j) {
          // pack tiles a..a+3 as bf16 pairs; a+4 stays f32
          unsigned int pkA = cvtpk(qer[rt][a][j],     qer[rt][a + 1][j]);
          unsigned int pkB = cvtpk(qer[rt][a + 2][j], qer[rt][a + 3][j]);
          const float  s5f = qer[rt][a + 4][j];
          const int srcl = (q << 4) | ((15 + r - q * 4 - j) & 15);
          unsigned int A = (unsigned int)__shfl((int)pkA, srcl);
          unsigned int B = (unsigned int)__shfl((int)pkB, srcl);
          const float g4 = __shfl(s5f, srcl);
          const float g0 = __builtin_bit_cast(float, A << 16);
          const float g1 = __builtin_bit_cast(float, A & 0xffff0000u);
          const float g2 = __builtin_bit_cast(float, B << 16);
          const float g3 = __builtin_bit_cast(float, B & 0xffff0000u);
          const bool hi = (r > q * 4 + j);
          const float b0 = hi ? g1 : g0;
          const float b1 = hi ? g2 : g1;
          const float b2 = hi ? g3 : g2;
          const float b3 = hi ? g4 : g3;
          const int A_ = rt * 16 + q * 4 + j - r - d0;   // keep iff ct*16 <= A_
          const float p0 = (A_ >= 0)  ? __expf(s4[rt][0][j] + b0) : 0.f;
          const float p1 = (A_ >= 16) ? __expf(s4[rt][1][j] + b1) : 0.f;
          const float p2 = (A_ >= 32) ? __expf(s4[rt][2][j] + b2) : 0.f;
          const float p3 = (A_ >= 48) ? __expf(s4[rt][3][j] + b3) : 0.f;
          lpart[rt][j] += (p0 + p1) + (p2 + p3);
          const int sl = rt * 16 + q * 4 + j;
          const unsigned long long pw =
              (unsigned long long)cvtpk(p0, p1) |
              ((unsigned long long)cvtpk(p2, p3) << 32);
          *(unsigned long long*)&p_lds[wv][sl][4 * r] = pw;   // t' = 4r+ct
        }
      }

      bf16x8 vf[4][2];
#pragma unroll
      for (int dc = 0; dc < 4; ++dc)
#pragma unroll
        for (int tc = 0; tc < 2; ++tc)
          vf[dc][tc] = *(const bf16x8*)(VL + tc * 2048 + dc * 512 + lane * 8);
      __builtin_amdgcn_s_setprio(1);
#pragma unroll
      for (int rt = 0; rt < 2; ++rt) {
        bf16x8 pf0 = *(const bf16x8*)(&p_lds[wv][rt * 16 + r][0] + q * 8);
        bf16x8 pf1 = *(const bf16x8*)(&p_lds[wv][rt * 16 + r][0] + 32 + q * 8);
#pragma unroll
        for (int dc = 0; dc < 4; ++dc)
          oacc[rt][dc] = MFMA(pf1, vf[dc][1], MFMA(pf0, vf[dc][0], oacc[rt][dc]));
      }
      __builtin_amdgcn_s_setprio(0);

#pragma unroll
      for (int rt = 0; rt < 2; ++rt) { qer[rt][0] = qer[rt][4]; qer[rt][1] = qer[rt][5]; }
    };

    ErSet eA, eB;
    loadE(eA, it0);

    int it = it0, cur = 0;
    while (true) {
      int nx = cur + 1; if (nx == 3) nx = 0;
      int itn = (it + 1 < it1) ? it + 1 : it1 - 1;
      stageKV(itn, nx);
      loadE(eB, itn);
      asm volatile("s_waitcnt vmcnt(12)\n\ts_barrier" ::: "memory");
      body(it, cur, eA);
      cur = nx;
      if (++it >= it1) break;
      nx = cur + 1; if (nx == 3) nx = 0;
      itn = (it + 1 < it1) ? it + 1 : it1 - 1;
      stageKV(itn, nx);
      loadE(eA, itn);
      asm volatile("s_waitcnt vmcnt(12)\n\ts_barrier" ::: "memory");
      body(it, cur, eB);
      cur = nx;
      if (++it >= it1) break;
    }

    // epilogue: partial sums (unnormalized)
#pragma unroll
    for (int rt = 0; rt < 2; ++rt)
#pragma unroll
      for (int j = 0; j < 4; ++j) {
        float ls = lpart[rt][j];
#pragma unroll
        for (int d = 1; d < 16; d <<= 1) ls += __shfl_xor(ls, d);
        const int row = wv * 32 + rt * 16 + q * 4 + j;
        if (po) {
#pragma unroll
          for (int dc = 0; dc < 4; ++dc)
            po[(size_t)row * 64 + dc * 16 + r] = oacc[rt][dc][j];
        } else {                                // fh: raw O into d_out
          const int ss = T * 128 + row;
#pragma unroll
          for (int dc = 0; dc < 4; ++dc)
            out[((size_t)(bb * SEQ_ + ss)) * DMODEL + hh * DHEAD + dc * 16 + r] = oacc[rt][dc][j];
        }
        if (r == 0) pl[row] = ls;
      }
  };

  // block = fh(TA) + sh(TB), 17 iters total
  int TA, a1, TB, b0, b1;
  if (role == 0) { TA = 15 - p; a1 = 16 - p; TB = p;      b0 = p + 1;  b1 = 2 * p + 2; }
  else           { TA = p;      a1 = p + 1;  TB = 15 - p; b0 = 16 - p; b1 = 32 - 2 * p; }

  run_strip(TA, 0, a1, nullptr,
            pL + ((size_t)(bh * 16 + TA)) * 256);
  run_strip(TB, b0, b1, pO1 + ((size_t)(bh * 16 + TB)) * 8192,
            pL + ((size_t)(bh * 16 + TB)) * 256 + 128);
}

// ---------------------------------------------------------------- reduce ----
// out = (out_fh + pO1_sh) / (l0 + l1) for every 128-row tile.
__global__ __launch_bounds__(256) void reduce_kernel(const float* __restrict__ pO1,
                                                     const float* __restrict__ pL,
                                                     float* __restrict__ out) {
  const int slot = blockIdx.x;                  // bh*16 + T
  const int bh = slot >> 4, T = slot & 15;
  const int bb = bh >> 4, hh = bh & 15;
  const int tid = threadIdx.x;
  const int row = tid >> 1, half = (tid & 1) * 32;

  const float l0 = pL[(size_t)slot * 256 + row];
  const float l1 = pL[(size_t)slot * 256 + 128 + row];
  const float inv = 1.0f / (l0 + l1);

  float* a = out + ((size_t)(bb * SEQ_) + T * 128 + row) * DMODEL + hh * DHEAD + half;
  const float* b = pO1 + (size_t)slot * 8192 + row * 64 + half;
#pragma unroll
  for (int k = 0; k < 8; ++k) {
    float4 x = ((const float4*)a)[k];
    float4 y = ((const float4*)b)[k];
    float4 o;
    o.x = (x.x + y.x) * inv; o.y = (x.y + y.y) * inv;
    o.z = (x.z + y.z) * inv; o.w = (x.w + y.w) * inv;
    ((float4*)a)[k] = o;
  }
}

// ------------------------------------------------------------------ launch ---
extern "C" void kernel_launch(void* const* d_in, const int* in_sizes, int n_in,
                              void* d_out, int out_size, void* d_ws, size_t ws_size,
                              hipStream_t stream) {
  const float* query = (const float*)d_in[0];
  const float* key   = (const float*)d_in[1];
  const float* value = (const float*)d_in[2];
  const float* Wq    = (const float*)d_in[3];
  const float* bq    = (const float*)d_in[4];
  const float* Wk    = (const float*)d_in[5];
  const float* bk    = (const float*)d_in[6];
  const float* Wv    = (const float*)d_in[7];
  const float* bv    = (const float*)d_in[8];
  const float* Er    = (const float*)d_in[9];

  char* ws = (char*)d_ws;
  unsigned short* qb   = (unsigned short*)(ws + (0u  << 20));  // 8MB
  unsigned short* ktil = (unsigned short*)(ws + (8u  << 20));  // 8MB
  unsigned short* vtil = (unsigned short*)(ws + (16u << 20));  // 8MB
  float*          pO1  = (float*)(ws + (24u << 20));           // 16MB [24,40) (Xq dead post-proj)
  float*          pL   = (float*)(ws + (40u << 20));           // 512KB (Xk dead post-proj)
  unsigned short* Xq   = (unsigned short*)(ws + (32u << 20));  // proj inputs (live only pre-attn)
  unsigned short* Xk   = (unsigned short*)(ws + (40u << 20));
  unsigned short* Xv   = (unsigned short*)(ws + (48u << 20));
  unsigned short* Wqb  = (unsigned short*)(ws + (56u << 20));  // 2MB
  unsigned short* Wkb  = (unsigned short*)(ws + (58u << 20));
  unsigned short* Wvb  = (unsigned short*)(ws + (60u << 20));
  unsigned short* Erb  = (unsigned short*)(ws + (62u << 20));  // 256KB

  conv3_kernel<<<dim3(2048, 3), 256, 0, stream>>>(query, key, value, Xq, Xk, Xv,
                                                  2 * SEQ_ * DMODEL);
  conv4_kernel<<<dim3(512, 4), 256, 0, stream>>>(Wq, Wk, Wv, Er,
                                                 Wqb, Wkb, Wvb, Erb,
                                                 DMODEL * DMODEL, SEQ_ * DHEAD);

  proj3_kernel<<<dim3(32, 8, 3), 256, 0, stream>>>(Xq, Xk, Xv, Wqb, Wkb, Wvb,
                                                   bq, bk, bv, qb, ktil, vtil);

  attn_kernel<<<dim3(512), 256, 0, stream>>>(qb, ktil, vtil, Erb,
                                             (float*)d_out, pO1, pL);

  reduce_kernel<<<dim3(512), 256, 0, stream>>>(pO1, pL, (float*)d_out);
}